// Round 10
// baseline (1440.100 us; speedup 1.0000x reference)
//
#include <hip/hip_runtime.h>

// ---------------------------------------------------------------------------
// MultiHeadAttention (full-width per-head projections), MI355X gfx950.
// Round 10: mixed-BK GEMM cores (pure parameter change, both replay-verified):
//   3-term (MT, G, scores): gemm_core32 == R8 core verbatim, BK=32, 32KB LDS
//   1-term (PV, Z, NT):     gemm_core64 == R9 core verbatim, BK=64, 32KB LDS
// Rationale: R9's 64KB 3-term tiles capped residency at 2 blocks/CU
// (Occupancy 15.7%); 32KB unlocks the grid-offered 3rd block -> +50% TLP to
// absorb barrier stalls (m114 cross-block overlap). Sync skeleton, XCD
// mappings, launcher: unchanged from R9.
// Math unchanged:
//   scores = softmax_t( 8*( x M_h x^T + w_t ) ),  M_h = Wq_h Wk_h^T
//   out    = sum_h P_h Z_h + bp,  Z_h = x N_h + bv_h Wp_h,  N_h = Wv_h Wp_h
// 3-term bf16 hi/lo split on the score path; bf16 elsewhere; fp32 softmax.
// ---------------------------------------------------------------------------

typedef __attribute__((ext_vector_type(8))) short bf16x8;
typedef __attribute__((ext_vector_type(4))) float fx4;

#define NB 8
#define NS 1024
#define ND 768
#define NH 12

__device__ __forceinline__ unsigned short f2bf(float x) {
    unsigned int u = __float_as_uint(x);
    u += 0x7fffu + ((u >> 16) & 1u);   // round-to-nearest-even bf16
    return (unsigned short)(u >> 16);
}
__device__ __forceinline__ float bf2f(unsigned short h) {
    return __uint_as_float(((unsigned int)h) << 16);
}

// async global->LDS, 16B per lane; LDS base must be wave-uniform.
__device__ __forceinline__ void gll16(const void* g, void* l) {
    __builtin_amdgcn_global_load_lds(
        (const __attribute__((address_space(1))) void*)g,
        (__attribute__((address_space(3))) void*)l, 16, 0, 0);
}

// ---------------- elementwise bodies ----------------------------------------
__device__ __forceinline__ void split_body(const float* __restrict__ in,
                                           unsigned short* __restrict__ hi,
                                           unsigned short* __restrict__ lo, int i) {
    float4 v = ((const float4*)in)[i];
    ushort4 h, l;
    h.x = f2bf(v.x); l.x = f2bf(v.x - bf2f(h.x));
    h.y = f2bf(v.y); l.y = f2bf(v.y - bf2f(h.y));
    h.z = f2bf(v.z); l.z = f2bf(v.z - bf2f(h.z));
    h.w = f2bf(v.w); l.w = f2bf(v.w - bf2f(h.w));
    ((ushort4*)hi)[i] = h;
    ((ushort4*)lo)[i] = l;
}

// ---------------------------------------------------------------------------
// gemm_core32 — R8 core VERBATIM (replay-verified): 128x128 tile, BK=32,
// 4 waves (2x2), single-buffer, per K-tile: sync -> stage -> sync -> ds+MFMA.
// LDS [128][32] bf16 tiles: A @0, B @8KB, A2 @16KB, B2 @24KB (3-term: 32KB).
// Swizzle: source chunk (lane&3)^((row>>1)&3), linear LDS dest, read offset
// (lg ^ ((row>>1)&3)) -> 0 bank conflicts (verified R4).
// C/D layout (HW-verified): col = lane&15, row = (lane>>4)*4 + reg.
// ---------------------------------------------------------------------------
template<int NTERMS, class Epi>
__device__ __forceinline__ void gemm_core32(
    char* __restrict__ smem,
    const unsigned short* __restrict__ Ah, const unsigned short* __restrict__ Al, int lda,
    const unsigned short* __restrict__ Bh, const unsigned short* __restrict__ Bl, int ldb,
    int K, Epi epi)
{
    const int t = threadIdx.x;
    const int lane = t & 63;
    const int w = t >> 6;
    const int wm = (w >> 1) << 6;
    const int wn = (w & 1) << 6;
    const int lr = lane & 15;
    const int lg = lane >> 4;

    const int srA = (w << 5) + (lane >> 2);
    const int swz = (srA >> 1) & 3;
    const int skb = (((lane & 3) ^ swz) << 4);
    const int ldso = w << 11;                // wave-uniform LDS byte offset

    const long ga0 = (long)srA * lda * 2 + skb;
    const long ga1 = ga0 + (long)lda * 32;   // +16 rows (bytes)
    const long gb0 = (long)srA * ldb * 2 + skb;
    const long gb1 = gb0 + (long)ldb * 32;

    const char* pAh = (const char*)Ah;
    const char* pBh = (const char*)Bh;
    const char* pAl = (const char*)Al;
    const char* pBl = (const char*)Bl;
    char* smA  = smem;
    char* smB  = smem + 8192;
    char* smA2 = smem + ((NTERMS == 3) ? 16384 : 0);
    char* smB2 = smem + ((NTERMS == 3) ? 24576 : 8192);

    int offA[4], offB[4];
    #pragma unroll
    for (int i = 0; i < 4; i++) {
        int ra = wm + (i << 4) + lr;
        offA[i] = ra * 32 + ((lg ^ ((ra >> 1) & 3)) << 3);   // ushort index
        int rb = wn + (i << 4) + lr;
        offB[i] = rb * 32 + ((lg ^ ((rb >> 1) & 3)) << 3);
    }

    fx4 acc[4][4] = {};

    for (int k0 = 0; k0 < K; k0 += 32) {
        const long kb2 = (long)k0 * 2;
        __syncthreads();
        gll16(pAh + ga0 + kb2, smA + ldso);
        gll16(pAh + ga1 + kb2, smA + ldso + 1024);
        gll16(pBh + gb0 + kb2, smB + ldso);
        gll16(pBh + gb1 + kb2, smB + ldso + 1024);
        if constexpr (NTERMS == 3) {
            gll16(pAl + ga0 + kb2, smA2 + ldso);
            gll16(pAl + ga1 + kb2, smA2 + ldso + 1024);
            gll16(pBl + gb0 + kb2, smB2 + ldso);
            gll16(pBl + gb1 + kb2, smB2 + ldso + 1024);
        }
        __syncthreads();

        bf16x8 fa[4], fb[4], fa2[4], fb2[4];
        #pragma unroll
        for (int i = 0; i < 4; i++) {
            fa[i] = *(const bf16x8*)((const unsigned short*)smA + offA[i]);
            fb[i] = *(const bf16x8*)((const unsigned short*)smB + offB[i]);
        }
        if constexpr (NTERMS == 3) {
            #pragma unroll
            for (int i = 0; i < 4; i++) {
                fa2[i] = *(const bf16x8*)((const unsigned short*)smA2 + offA[i]);
                fb2[i] = *(const bf16x8*)((const unsigned short*)smB2 + offB[i]);
            }
        }
        #pragma unroll
        for (int i = 0; i < 4; i++)
            #pragma unroll
            for (int j = 0; j < 4; j++) {
                acc[i][j] = __builtin_amdgcn_mfma_f32_16x16x32_bf16(fa[i], fb[j], acc[i][j], 0, 0, 0);
                if constexpr (NTERMS == 3) {
                    acc[i][j] = __builtin_amdgcn_mfma_f32_16x16x32_bf16(fa[i], fb2[j], acc[i][j], 0, 0, 0);
                    acc[i][j] = __builtin_amdgcn_mfma_f32_16x16x32_bf16(fa2[i], fb[j], acc[i][j], 0, 0, 0);
                }
            }
    }

    #pragma unroll
    for (int i = 0; i < 4; i++)
        #pragma unroll
        for (int j = 0; j < 4; j++)
            #pragma unroll
            for (int r = 0; r < 4; r++)
                epi(wm + (i << 4) + (lg << 2) + r, wn + (j << 4) + lr, acc[i][j][r]);
}

// ---------------------------------------------------------------------------
// gemm_core64 — R9 core VERBATIM (replay-verified): BK=64, [128][64] tiles
// (16KB each; 1-term: 32KB). Swizzle pc = c_log ^ (row&7); staging source
// chunk (lane&7)^(lane>>3), linear LDS dest. Same sync skeleton.
// ---------------------------------------------------------------------------
template<int NTERMS, class Epi>
__device__ __forceinline__ void gemm_core64(
    char* __restrict__ smem,
    const unsigned short* __restrict__ Ah, const unsigned short* __restrict__ Al, int lda,
    const unsigned short* __restrict__ Bh, const unsigned short* __restrict__ Bl, int ldb,
    int K, Epi epi)
{
    constexpr int TILE = 16384;              // bytes per [128][64] bf16 tile

    const int t = threadIdx.x;
    const int lane = t & 63;
    const int w = t >> 6;
    const int wm = (w >> 1) << 6;
    const int wn = (w & 1) << 6;
    const int lr = lane & 15;
    const int lg = lane >> 4;

    const int l3 = lane >> 3;
    const int cs = (lane & 7) ^ l3;
    const int ldsw = w << 12;                // wave-uniform LDS byte offset

    const long gsA = (long)(w * 32 + l3) * lda * 2 + cs * 16;
    const long gsB = (long)(w * 32 + l3) * ldb * 2 + cs * 16;
    const long giA = (long)lda * 16;         // +8 rows, in bytes
    const long giB = (long)ldb * 16;

    const char* pAh = (const char*)Ah;
    const char* pBh = (const char*)Bh;
    const char* pAl = (const char*)Al;
    const char* pBl = (const char*)Bl;
    char* smA  = smem;
    char* smB  = smem + TILE;
    char* smA2 = smem + ((NTERMS == 3) ? 2 * TILE : 0);
    char* smB2 = smem + ((NTERMS == 3) ? 3 * TILE : TILE);

    int rowA[4], rowB[4];
    #pragma unroll
    for (int i = 0; i < 4; i++) {
        rowA[i] = (wm + (i << 4) + lr) << 6;   // ushort index of row base
        rowB[i] = (wn + (i << 4) + lr) << 6;
    }
    const int lr7 = lr & 7;

    fx4 acc[4][4] = {};

    for (int k0 = 0; k0 < K; k0 += 64) {
        const long kb2 = (long)k0 * 2;
        __syncthreads();
        #pragma unroll
        for (int ii = 0; ii < 4; ii++) {
            const int lo = ldsw + (ii << 10);
            gll16(pAh + gsA + ii * giA + kb2, smA + lo);
            gll16(pBh + gsB + ii * giB + kb2, smB + lo);
            if constexpr (NTERMS == 3) {
                gll16(pAl + gsA + ii * giA + kb2, smA2 + lo);
                gll16(pBl + gsB + ii * giB + kb2, smB2 + lo);
            }
        }
        __syncthreads();

        #pragma unroll
        for (int kk = 0; kk < 2; kk++) {
            const int pc = (((kk << 2) + lg) ^ lr7) << 3;   // ushort offset
            bf16x8 fa[4], fb[4], fa2[4], fb2[4];
            #pragma unroll
            for (int i = 0; i < 4; i++) {
                fa[i] = *(const bf16x8*)((const unsigned short*)smA + rowA[i] + pc);
                fb[i] = *(const bf16x8*)((const unsigned short*)smB + rowB[i] + pc);
            }
            if constexpr (NTERMS == 3) {
                #pragma unroll
                for (int i = 0; i < 4; i++) {
                    fa2[i] = *(const bf16x8*)((const unsigned short*)smA2 + rowA[i] + pc);
                    fb2[i] = *(const bf16x8*)((const unsigned short*)smB2 + rowB[i] + pc);
                }
            }
            #pragma unroll
            for (int i = 0; i < 4; i++)
                #pragma unroll
                for (int j = 0; j < 4; j++) {
                    acc[i][j] = __builtin_amdgcn_mfma_f32_16x16x32_bf16(fa[i], fb[j], acc[i][j], 0, 0, 0);
                    if constexpr (NTERMS == 3) {
                        acc[i][j] = __builtin_amdgcn_mfma_f32_16x16x32_bf16(fa[i], fb2[j], acc[i][j], 0, 0, 0);
                        acc[i][j] = __builtin_amdgcn_mfma_f32_16x16x32_bf16(fa2[i], fb[j], acc[i][j], 0, 0, 0);
                    }
                }
        }
    }

    #pragma unroll
    for (int i = 0; i < 4; i++)
        #pragma unroll
        for (int j = 0; j < 4; j++)
            #pragma unroll
            for (int r = 0; r < 4; r++)
                epi(wm + (i << 4) + (lg << 2) + r, wn + (j << 4) + lr, acc[i][j][r]);
}

// ---------------- softmax body (wave per row, 4 rows per block) --------------
__device__ __forceinline__ void softmax_rows(float* __restrict__ Sc, int blk) {
    int row = blk * 4 + ((int)threadIdx.x >> 6);
    int lane = threadIdx.x & 63;
    float* rp = Sc + (long)row * NS;
    const float4* src = (const float4*)rp + (lane << 2);
    float v[16];
    #pragma unroll
    for (int i = 0; i < 4; i++) {
        float4 a = src[i];
        v[i * 4 + 0] = a.x; v[i * 4 + 1] = a.y; v[i * 4 + 2] = a.z; v[i * 4 + 3] = a.w;
    }
    float m = v[0];
    #pragma unroll
    for (int i = 1; i < 16; i++) m = fmaxf(m, v[i]);
    #pragma unroll
    for (int o = 32; o > 0; o >>= 1) m = fmaxf(m, __shfl_xor(m, o));
    float s = 0.f, p[16];
    #pragma unroll
    for (int i = 0; i < 16; i++) { p[i] = __expf((v[i] - m) * 8.0f); s += p[i]; }
    #pragma unroll
    for (int o = 32; o > 0; o >>= 1) s += __shfl_xor(s, o);
    float inv = 1.0f / s;
    unsigned int wrd[8];
    #pragma unroll
    for (int i = 0; i < 8; i++) {
        unsigned int u0 = f2bf(p[2 * i] * inv);
        unsigned int u1 = f2bf(p[2 * i + 1] * inv);
        wrd[i] = u0 | (u1 << 16);
    }
    uint4* dst = (uint4*)((unsigned short*)rp + (lane << 4));
    dst[0] = make_uint4(wrd[0], wrd[1], wrd[2], wrd[3]);
    dst[1] = make_uint4(wrd[4], wrd[5], wrd[6], wrd[7]);
}

// ------------------------- fused setup kernels -------------------------------
// setup1: split x (6144) | split Wq (6912) | split Wk (6912) | rk (2304).
__global__ void k_setup1(
    const float* __restrict__ x, unsigned short* __restrict__ xh, unsigned short* __restrict__ xl,
    const float* __restrict__ Wq, unsigned short* __restrict__ Wqh, unsigned short* __restrict__ Wql,
    const float* __restrict__ Wk, unsigned short* __restrict__ Wkh, unsigned short* __restrict__ Wkl,
    const float* __restrict__ bq, float* __restrict__ rk)
{
    const int bx = blockIdx.x;
    if (bx < 6144) {
        split_body(x, xh, xl, bx * 256 + threadIdx.x);
    } else if (bx < 13056) {
        split_body(Wq, Wqh, Wql, (bx - 6144) * 256 + threadIdx.x);
    } else if (bx < 19968) {
        split_body(Wk, Wkh, Wkl, (bx - 13056) * 256 + threadIdx.x);
    } else {
        const int idx = bx - 19968;            // [0,2304)
        const int h = idx / 192;
        const int d = (idx % 192) * 4 + ((int)threadIdx.x >> 6);
        const int lane = threadIdx.x & 63;
        const float4* row = (const float4*)(Wk + ((long)h * ND + d) * ND);
        const float4* bv4 = (const float4*)(bq + h * ND);
        float acc = 0.f;
        #pragma unroll
        for (int i = 0; i < 3; i++) {
            float4 a = row[lane + (i << 6)];
            float4 b = bv4[lane + (i << 6)];
            acc += a.x * b.x + a.y * b.y + a.z * b.z + a.w * b.w;
        }
        #pragma unroll
        for (int o = 32; o > 0; o >>= 1) acc += __shfl_xor(acc, o);
        if (lane == 0) rk[h * ND + d] = acc;
    }
}

// setup2: k_MT (432, 3-term gemm BK=32, XCD-chunked) | k_w (2048).
__global__ __launch_bounds__(256, 2) void k_setup2(
    const unsigned short* __restrict__ Wkh, const unsigned short* __restrict__ Wkl,
    const unsigned short* __restrict__ Wqh, const unsigned short* __restrict__ Wql,
    unsigned short* __restrict__ MTh, unsigned short* __restrict__ MTl,
    const float* __restrict__ x, const float* __restrict__ rk, float* __restrict__ w_all)
{
    __shared__ __align__(16) char smem[36864];   // 32KB gemm | 36KB srk
    const int bx = blockIdx.x;
    if (bx < 432) {
        const int tid = (bx & 7) * 54 + (bx >> 3);   // XCD-contiguous tiles
        const int n0 = (tid % 6) << 7;
        const int m0 = ((tid / 6) % 6) << 7;
        const long hw = (long)(tid / 36) * (ND * ND);
        unsigned short* oh = MTh + hw + (long)m0 * ND + n0;
        unsigned short* ol = MTl + hw + (long)m0 * ND + n0;
        gemm_core32<3>(smem, Wkh + hw + (long)m0 * ND, Wkl + hw + (long)m0 * ND, ND,
                       Wqh + hw + (long)n0 * ND, Wql + hw + (long)n0 * ND, ND, ND,
                       [=](int r, int c, float v) {
                           unsigned short hh = f2bf(v);
                           oh[r * ND + c] = hh;
                           ol[r * ND + c] = f2bf(v - bf2f(hh));
                       });
    } else {
        float* srk = (float*)smem;               // 9216 floats = 36KB
        for (int i = threadIdx.x; i < NH * ND; i += 256) srk[i] = rk[i];
        __syncthreads();
        const int row = (bx - 432) * 4 + ((int)threadIdx.x >> 6);
        const int lane = threadIdx.x & 63;
        const float4* xr = (const float4*)(x + (long)row * ND);
        float4 xa[3];
        #pragma unroll
        for (int i = 0; i < 3; i++) xa[i] = xr[lane + (i << 6)];
        for (int h = 0; h < NH; h++) {
            const float* r = srk + h * ND;
            float acc = 0.f;
            #pragma unroll
            for (int i = 0; i < 3; i++) {
                int e = (lane + (i << 6)) << 2;
                acc += xa[i].x * r[e] + xa[i].y * r[e + 1]
                     + xa[i].z * r[e + 2] + xa[i].w * r[e + 3];
            }
            #pragma unroll
            for (int o = 32; o > 0; o >>= 1) acc += __shfl_xor(acc, o);
            if (lane == 0) w_all[h * (NB * NS) + row] = acc;
        }
    }
}

// setup3 (after MT consumed Wq/Wk splits): castbf Wv (6912) | transpose Wp (1728).
__global__ void k_setup3(const float* __restrict__ Wv, unsigned short* __restrict__ Wvb,
                         const float* __restrict__ Wp, unsigned short* __restrict__ WpT)
{
    __shared__ float tile[64][65];
    const int bx = blockIdx.x;
    if (bx < 6912) {
        int i = bx * 256 + threadIdx.x;
        float4 v = ((const float4*)Wv)[i];
        ushort4 h;
        h.x = f2bf(v.x); h.y = f2bf(v.y); h.z = f2bf(v.z); h.w = f2bf(v.w);
        ((ushort4*)Wvb)[i] = h;
    } else {
        const int idx = bx - 6912;             // [0,1728)
        const int c0 = (idx % 12) * 64;
        const int r0 = ((idx / 12) % 12) * 64;
        const long zo = (long)(idx / 144) * (ND * ND);
        const float* in = Wp + zo;
        unsigned short* oh = WpT + zo;
        const int tc = threadIdx.x & 63, t4 = threadIdx.x >> 6;
        #pragma unroll
        for (int i = 0; i < 16; i++) {
            int r = (i << 2) + t4;
            tile[r][tc] = in[(long)(r0 + r) * ND + c0 + tc];
        }
        __syncthreads();
        #pragma unroll
        for (int i = 0; i < 16; i++) {
            int c = (i << 2) + t4;
            oh[(long)(c0 + c) * ND + r0 + tc] = f2bf(tile[tc][c]);
        }
    }
}

// setup4: k_NT (432, 1-term gemm BK=64, XCD-chunked) | k_sh (2304).
__global__ __launch_bounds__(256, 2) void k_setup4(
    const unsigned short* __restrict__ WpT, const unsigned short* __restrict__ Wvb,
    unsigned short* __restrict__ NTo, const float* __restrict__ bv,
    float* __restrict__ s_all)
{
    __shared__ __align__(16) char smem[32768];
    const int bx = blockIdx.x;
    if (bx < 432) {
        const int tid = (bx & 7) * 54 + (bx >> 3);   // XCD-contiguous tiles
        const int n0 = (tid % 6) << 7;
        const int m0 = ((tid / 6) % 6) << 7;
        const long hw = (long)(tid / 36) * (ND * ND);
        unsigned short* o = NTo + hw + (long)m0 * ND + n0;
        gemm_core64<1>(smem, WpT + hw + (long)m0 * ND, nullptr, ND,
                       Wvb + hw + (long)n0 * ND, nullptr, ND, ND,
                       [=](int r, int c, float v) { o[r * ND + c] = f2bf(v); });
    } else {
        const int idx = bx - 432;              // [0,2304)
        const int h = idx / 192;
        const int j = (idx % 192) * 4 + ((int)threadIdx.x >> 6);
        const int lane = threadIdx.x & 63;
        const ushort4* row = (const ushort4*)(WpT + ((long)h * ND + j) * ND);
        const float* bvh = bv + h * ND;
        float acc = 0.f;
        #pragma unroll
        for (int i = 0; i < 3; i++) {
            int c = lane + (i << 6);
            ushort4 u = row[c];
            int e = c << 2;
            acc += bf2f(u.x) * bvh[e] + bf2f(u.y) * bvh[e + 1]
                 + bf2f(u.z) * bvh[e + 2] + bf2f(u.w) * bvh[e + 3];
        }
        #pragma unroll
        for (int o = 32; o > 0; o >>= 1) acc += __shfl_xor(acc, o);
        if (lane == 0) s_all[h * ND + j] = acc;
    }
}

// ------------------------- per-head kernels (XCD-remapped) -------------------

// G = x * M_h (split out), head-0 bootstrap. flat grid 384. BK=32.
__global__ __launch_bounds__(256, 2) void k_G0(
    const unsigned short* __restrict__ xh, const unsigned short* __restrict__ xl,
    const unsigned short* __restrict__ MTh, const unsigned short* __restrict__ MTl,
    unsigned short* __restrict__ Gh, unsigned short* __restrict__ Gl)
{
    __shared__ __align__(16) char smem[32768];
    const int bx = blockIdx.x;
    const int xcd = bx & 7, idx = bx >> 3;
    const int m0 = (xcd * 8 + idx / 6) << 7;
    const int n0 = (idx % 6) << 7;
    unsigned short* oh = Gh + (long)m0 * ND + n0;
    unsigned short* ol = Gl + (long)m0 * ND + n0;
    gemm_core32<3>(smem, xh + (long)m0 * ND, xl + (long)m0 * ND, ND,
                   MTh + (long)n0 * ND, MTl + (long)n0 * ND, ND, ND,
                   [=](int r, int c, float v) {
                       unsigned short hh = f2bf(v);
                       oh[(long)r * ND + c] = hh;
                       ol[(long)r * ND + c] = f2bf(v - bf2f(hh));
                   });
}

// fused: blocks [0,512) scores = G.x^T + w (xcd = batch, BK=32);
//        blocks [512,896) Z = x*NT_h + s_h -> ZT (xcd-banded m, BK=64).
__global__ __launch_bounds__(256, 2) void k_SZ(
    const unsigned short* __restrict__ Gh, const unsigned short* __restrict__ Gl,
    const unsigned short* __restrict__ xh, const unsigned short* __restrict__ xl,
    const float* __restrict__ wv, float* __restrict__ Sc,
    const unsigned short* __restrict__ NTh, const float* __restrict__ sh,
    unsigned short* __restrict__ ZT)
{
    __shared__ __align__(16) char smem[32768];
    const int bx = blockIdx.x;
    if (bx < 512) {
        const int bl = bx & 7, idx = bx >> 3;
        const int m0 = (idx >> 3) << 7;
        const int n0 = (idx & 7) << 7;
        const long ao = ((long)bl * NS + m0) * ND;
        const long bo = ((long)bl * NS + n0) * ND;
        const float* ww = wv + bl * NS + n0;
        float* out = Sc + ((long)bl * NS + m0) * NS + n0;
        gemm_core32<3>(smem, Gh + ao, Gl + ao, ND, xh + bo, xl + bo, ND, ND,
                       [=](int r, int c, float v) { out[(long)r * NS + c] = v + ww[c]; });
    } else {
        const int g = bx - 512;
        const int xcd = g & 7, idx = g >> 3;
        const int m0 = (xcd * 8 + idx / 6) << 7;
        const int n0 = (idx % 6) << 7;
        const int bl = m0 >> 10;
        const int s0 = m0 & (NS - 1);
        unsigned short* zt = ZT + (long)bl * (ND * NS);
        gemm_core64<1>(smem, xh + (long)m0 * ND, nullptr, ND,
                       NTh + (long)n0 * ND, nullptr, ND, ND,
                       [=](int r, int c, float v) {
                           zt[(long)(n0 + c) * NS + s0 + r] = f2bf(v + sh[n0 + c]);
                       });
    }
}

// pure softmax, in place. grid 2048 (8192 rows).
__global__ __launch_bounds__(256) void k_SM(float* __restrict__ Sc) {
    softmax_rows(Sc, blockIdx.x);
}

// fused: blocks [0,384) out += P*Z (xcd = batch, BK=64);
//        blocks [384,768) G(next head) = x * M_{h+1} (xcd-banded m, BK=32).
template<int MODE>   // 0: first head (write + bias), 1: accumulate
__global__ __launch_bounds__(256, 2) void k_PVG(
    const unsigned short* __restrict__ P, const unsigned short* __restrict__ ZT,
    const float* __restrict__ bp, float* __restrict__ outp,
    const unsigned short* __restrict__ xh, const unsigned short* __restrict__ xl,
    const unsigned short* __restrict__ MTh, const unsigned short* __restrict__ MTl,
    unsigned short* __restrict__ Gh, unsigned short* __restrict__ Gl)
{
    __shared__ __align__(16) char smem[32768];
    const int bx = blockIdx.x;
    if (bx < 384) {
        const int bl = bx & 7, idx = bx >> 3;
        const int m0 = (idx / 6) << 7;
        const int n0 = (idx % 6) << 7;
        const unsigned short* A = P + ((long)bl * NS + m0) * (2 * NS);
        const unsigned short* B = ZT + (long)bl * (ND * NS) + (long)n0 * NS;
        float* o = outp + ((long)bl * NS + m0) * ND + n0;
        const float* bi = bp + n0;
        gemm_core64<1>(smem, A, nullptr, 2 * NS, B, nullptr, NS, NS,
                       [=](int r, int c, float v) {
                           float* d = o + (long)r * ND + c;
                           if constexpr (MODE == 0) *d = v + bi[c];
                           else *d += v;
                       });
    } else {
        const int g = bx - 384;
        const int xcd = g & 7, idx = g >> 3;
        const int m0 = (xcd * 8 + idx / 6) << 7;
        const int n0 = (idx % 6) << 7;
        unsigned short* oh = Gh + (long)m0 * ND + n0;
        unsigned short* ol = Gl + (long)m0 * ND + n0;
        gemm_core32<3>(smem, xh + (long)m0 * ND, xl + (long)m0 * ND, ND,
                       MTh + (long)n0 * ND, MTl + (long)n0 * ND, ND, ND,
                       [=](int r, int c, float v) {
                           unsigned short hh = f2bf(v);
                           oh[(long)r * ND + c] = hh;
                           ol[(long)r * ND + c] = f2bf(v - bf2f(hh));
                       });
    }
}

// ---------------------------------------------------------------------------

extern "C" void kernel_launch(void* const* d_in, const int* in_sizes, int n_in,
                              void* d_out, int out_size, void* d_ws, size_t ws_size,
                              hipStream_t stream) {
    (void)in_sizes; (void)n_in; (void)out_size; (void)ws_size;
    const float* x  = (const float*)d_in[0];
    const float* Wq = (const float*)d_in[1];
    const float* bq = (const float*)d_in[2];
    const float* Wk = (const float*)d_in[3];
    const float* bk = (const float*)d_in[4];  (void)bk;  // cancels in softmax
    const float* Wv = (const float*)d_in[5];
    const float* bv = (const float*)d_in[6];
    const float* Wp = (const float*)d_in[7];
    const float* bp = (const float*)d_in[8];

    const size_t nx  = (size_t)NB * NS * ND;   // 6,291,456
    const size_t nw  = (size_t)NH * ND * ND;   // 7,077,888

    char* p = (char*)d_ws;
    auto alloc = [&](size_t bytes) -> void* {
        void* r = (void*)p;
        p += (bytes + 255) & ~(size_t)255;
        return r;
    };
    // persistent
    unsigned short* xh   = (unsigned short*)alloc(nx * 2);
    unsigned short* xl   = (unsigned short*)alloc(nx * 2);
    unsigned short* MTh  = (unsigned short*)alloc(nw * 2);
    unsigned short* MTl  = (unsigned short*)alloc(nw * 2);
    unsigned short* NTb  = (unsigned short*)alloc(nw * 2);
    float*          rk   = (float*)alloc((size_t)NH * ND * 4);
    float*          s_all= (float*)alloc((size_t)NH * ND * 4);
    float*          w_all= (float*)alloc((size_t)NH * NB * NS * 4);
    // union region U: phase A = {Wq,Wk splits | Wvb,WpT}; phase B = {G,Sc,ZT}
    char* U = (char*)alloc(2 * nx * 2 + ((size_t)NB * NS * NS * 4) + ((size_t)NB * NS * ND * 2));
    // phase A views
    unsigned short* Wqh = (unsigned short*)U;
    unsigned short* Wql = Wqh + nw;
    unsigned short* Wkh = Wql + nw;
    unsigned short* Wkl = Wkh + nw;
    unsigned short* Wvb = (unsigned short*)U;        // after MT done
    unsigned short* WpT = Wvb + nw;
    // phase B views
    unsigned short* Gh = (unsigned short*)U;
    unsigned short* Gl = Gh + nx;
    float*          Sc = (float*)(Gl + nx);
    unsigned short* ZT = (unsigned short*)(Sc + (size_t)NB * NS * NS);

    // ---------------- setup (4 fused launches) ----------------
    k_setup1<<<22272, 256, 0, stream>>>(x, xh, xl, Wq, Wqh, Wql, Wk, Wkh, Wkl, bq, rk);
    k_setup2<<<2480, 256, 0, stream>>>(Wkh, Wkl, Wqh, Wql, MTh, MTl, x, rk, w_all);
    k_setup3<<<8640, 256, 0, stream>>>(Wv, Wvb, Wp, WpT);
    k_setup4<<<2736, 256, 0, stream>>>(WpT, Wvb, NTb, bv, s_all);

    // ---------------- per-head pipeline ----------------
    k_G0<<<384, 256, 0, stream>>>(xh, xl, MTh, MTl, Gh, Gl);
    for (int h = 0; h < NH; h++) {
        const long hwn = (long)(h + 1) * ND * ND;   // next head's M
        k_SZ<<<896, 256, 0, stream>>>(Gh, Gl, xh, xl, w_all + (long)h * NB * NS,
                                      Sc, NTb + (long)h * ND * ND, s_all + h * ND, ZT);
        k_SM<<<2048, 256, 0, stream>>>(Sc);
        const int ng = (h + 1 < NH) ? 768 : 384;
        if (h == 0)
            k_PVG<0><<<ng, 256, 0, stream>>>((unsigned short*)Sc, ZT, bp, (float*)d_out,
                                             xh, xl, MTh + hwn, MTl + hwn, Gh, Gl);
        else
            k_PVG<1><<<ng, 256, 0, stream>>>((unsigned short*)Sc, ZT, bp, (float*)d_out,
                                             xh, xl,
                                             MTh + ((h + 1 < NH) ? hwn : 0),
                                             MTl + ((h + 1 < NH) ? hwn : 0), Gh, Gl);
    }
}

// Round 11
// 1417.508 us; speedup vs baseline: 1.0159x; 1.0159x over previous
//
#include <hip/hip_runtime.h>

// ---------------------------------------------------------------------------
// MultiHeadAttention (full-width per-head projections), MI355X gfx950.
// Round 11: revert to R9's all-BK=64 config (R10's BK=32 3-term regressed:
// occupancy up, time down -> barrier count binds, not TLP) + head-grouped PV
// accumulation: P packed per head, one PV kernel per NG-head group runs the
// verbatim K-loop NG times accumulating in registers -> d_out round-trips
// 12 -> 12/NG (575 MB -> 125 MB HBM at NG=4). ws_size ladder NG=4 -> 2 ->
// R9-verbatim fallback. All K-loop bodies byte-identical to the
// replay-verified core64; only dataflow/epilogues change.
// Math unchanged:
//   scores = softmax_t( 8*( x M_h x^T + w_t ) ),  M_h = Wq_h Wk_h^T
//   out    = sum_h P_h Z_h + bp,  Z_h = x N_h + bv_h Wp_h,  N_h = Wv_h Wp_h
// ---------------------------------------------------------------------------

typedef __attribute__((ext_vector_type(8))) short bf16x8;
typedef __attribute__((ext_vector_type(4))) float fx4;

#define NB 8
#define NS 1024
#define ND 768
#define NH 12

__device__ __forceinline__ unsigned short f2bf(float x) {
    unsigned int u = __float_as_uint(x);
    u += 0x7fffu + ((u >> 16) & 1u);   // round-to-nearest-even bf16
    return (unsigned short)(u >> 16);
}
__device__ __forceinline__ float bf2f(unsigned short h) {
    return __uint_as_float(((unsigned int)h) << 16);
}

// async global->LDS, 16B per lane; LDS base must be wave-uniform.
__device__ __forceinline__ void gll16(const void* g, void* l) {
    __builtin_amdgcn_global_load_lds(
        (const __attribute__((address_space(1))) void*)g,
        (__attribute__((address_space(3))) void*)l, 16, 0, 0);
}

// ---------------- elementwise bodies ----------------------------------------
__device__ __forceinline__ void split_body(const float* __restrict__ in,
                                           unsigned short* __restrict__ hi,
                                           unsigned short* __restrict__ lo, int i) {
    float4 v = ((const float4*)in)[i];
    ushort4 h, l;
    h.x = f2bf(v.x); l.x = f2bf(v.x - bf2f(h.x));
    h.y = f2bf(v.y); l.y = f2bf(v.y - bf2f(h.y));
    h.z = f2bf(v.z); l.z = f2bf(v.z - bf2f(h.z));
    h.w = f2bf(v.w); l.w = f2bf(v.w - bf2f(h.w));
    ((ushort4*)hi)[i] = h;
    ((ushort4*)lo)[i] = l;
}

// ---------------------------------------------------------------------------
// gemm_core64 — replay-verified (R9): 128x128 tile, BK=64, 4 waves (2x2),
// single-buffer, per K-tile: sync -> stage (global_load_lds) -> sync -> ds+MFMA.
// LDS [128][64] bf16 tiles (16KB each). Swizzle pc = c_log ^ (row&7);
// staging source chunk (lane&7)^(lane>>3), linear LDS dest -> 0 conflicts.
// C/D layout (HW-verified): col = lane&15, row = (lane>>4)*4 + reg.
// ---------------------------------------------------------------------------
template<int NTERMS, class Epi>
__device__ __forceinline__ void gemm_core64(
    char* __restrict__ smem,
    const unsigned short* __restrict__ Ah, const unsigned short* __restrict__ Al, int lda,
    const unsigned short* __restrict__ Bh, const unsigned short* __restrict__ Bl, int ldb,
    int K, Epi epi)
{
    constexpr int TILE = 16384;              // bytes per [128][64] bf16 tile

    const int t = threadIdx.x;
    const int lane = t & 63;
    const int w = t >> 6;
    const int wm = (w >> 1) << 6;
    const int wn = (w & 1) << 6;
    const int lr = lane & 15;
    const int lg = lane >> 4;

    const int l3 = lane >> 3;
    const int cs = (lane & 7) ^ l3;
    const int ldsw = w << 12;                // wave-uniform LDS byte offset

    const long gsA = (long)(w * 32 + l3) * lda * 2 + cs * 16;
    const long gsB = (long)(w * 32 + l3) * ldb * 2 + cs * 16;
    const long giA = (long)lda * 16;         // +8 rows, in bytes
    const long giB = (long)ldb * 16;

    const char* pAh = (const char*)Ah;
    const char* pBh = (const char*)Bh;
    const char* pAl = (const char*)Al;
    const char* pBl = (const char*)Bl;
    char* smA  = smem;
    char* smB  = smem + TILE;
    char* smA2 = smem + ((NTERMS == 3) ? 2 * TILE : 0);
    char* smB2 = smem + ((NTERMS == 3) ? 3 * TILE : TILE);

    int rowA[4], rowB[4];
    #pragma unroll
    for (int i = 0; i < 4; i++) {
        rowA[i] = (wm + (i << 4) + lr) << 6;   // ushort index of row base
        rowB[i] = (wn + (i << 4) + lr) << 6;
    }
    const int lr7 = lr & 7;

    fx4 acc[4][4] = {};

    for (int k0 = 0; k0 < K; k0 += 64) {
        const long kb2 = (long)k0 * 2;
        __syncthreads();
        #pragma unroll
        for (int ii = 0; ii < 4; ii++) {
            const int lo = ldsw + (ii << 10);
            gll16(pAh + gsA + ii * giA + kb2, smA + lo);
            gll16(pBh + gsB + ii * giB + kb2, smB + lo);
            if constexpr (NTERMS == 3) {
                gll16(pAl + gsA + ii * giA + kb2, smA2 + lo);
                gll16(pBl + gsB + ii * giB + kb2, smB2 + lo);
            }
        }
        __syncthreads();

        #pragma unroll
        for (int kk = 0; kk < 2; kk++) {
            const int pc = (((kk << 2) + lg) ^ lr7) << 3;   // ushort offset
            bf16x8 fa[4], fb[4], fa2[4], fb2[4];
            #pragma unroll
            for (int i = 0; i < 4; i++) {
                fa[i] = *(const bf16x8*)((const unsigned short*)smA + rowA[i] + pc);
                fb[i] = *(const bf16x8*)((const unsigned short*)smB + rowB[i] + pc);
            }
            if constexpr (NTERMS == 3) {
                #pragma unroll
                for (int i = 0; i < 4; i++) {
                    fa2[i] = *(const bf16x8*)((const unsigned short*)smA2 + rowA[i] + pc);
                    fb2[i] = *(const bf16x8*)((const unsigned short*)smB2 + rowB[i] + pc);
                }
            }
            #pragma unroll
            for (int i = 0; i < 4; i++)
                #pragma unroll
                for (int j = 0; j < 4; j++) {
                    acc[i][j] = __builtin_amdgcn_mfma_f32_16x16x32_bf16(fa[i], fb[j], acc[i][j], 0, 0, 0);
                    if constexpr (NTERMS == 3) {
                        acc[i][j] = __builtin_amdgcn_mfma_f32_16x16x32_bf16(fa[i], fb2[j], acc[i][j], 0, 0, 0);
                        acc[i][j] = __builtin_amdgcn_mfma_f32_16x16x32_bf16(fa2[i], fb[j], acc[i][j], 0, 0, 0);
                    }
                }
        }
    }

    #pragma unroll
    for (int i = 0; i < 4; i++)
        #pragma unroll
        for (int j = 0; j < 4; j++)
            #pragma unroll
            for (int r = 0; r < 4; r++)
                epi(wm + (i << 4) + (lg << 2) + r, wn + (j << 4) + lr, acc[i][j][r]);
}

// ---------------- softmax bodies (wave per row, 4 rows per block) ------------
// common compute; dst = where to write bf16 P row (dstride ushorts per row)
__device__ __forceinline__ void softmax_row_core(const float* __restrict__ rp,
                                                 unsigned short* __restrict__ drow,
                                                 int lane) {
    const float4* src = (const float4*)rp + (lane << 2);
    float v[16];
    #pragma unroll
    for (int i = 0; i < 4; i++) {
        float4 a = src[i];
        v[i * 4 + 0] = a.x; v[i * 4 + 1] = a.y; v[i * 4 + 2] = a.z; v[i * 4 + 3] = a.w;
    }
    float m = v[0];
    #pragma unroll
    for (int i = 1; i < 16; i++) m = fmaxf(m, v[i]);
    #pragma unroll
    for (int o = 32; o > 0; o >>= 1) m = fmaxf(m, __shfl_xor(m, o));
    float s = 0.f, p[16];
    #pragma unroll
    for (int i = 0; i < 16; i++) { p[i] = __expf((v[i] - m) * 8.0f); s += p[i]; }
    #pragma unroll
    for (int o = 32; o > 0; o >>= 1) s += __shfl_xor(s, o);
    float inv = 1.0f / s;
    unsigned int wrd[8];
    #pragma unroll
    for (int i = 0; i < 8; i++) {
        unsigned int u0 = f2bf(p[2 * i] * inv);
        unsigned int u1 = f2bf(p[2 * i + 1] * inv);
        wrd[i] = u0 | (u1 << 16);
    }
    uint4* dst = (uint4*)(drow + (lane << 4));
    dst[0] = make_uint4(wrd[0], wrd[1], wrd[2], wrd[3]);
    dst[1] = make_uint4(wrd[4], wrd[5], wrd[6], wrd[7]);
}

// ------------------------- fused setup kernels (R9 verbatim) -----------------
__global__ void k_setup1(
    const float* __restrict__ x, unsigned short* __restrict__ xh, unsigned short* __restrict__ xl,
    const float* __restrict__ Wq, unsigned short* __restrict__ Wqh, unsigned short* __restrict__ Wql,
    const float* __restrict__ Wk, unsigned short* __restrict__ Wkh, unsigned short* __restrict__ Wkl,
    const float* __restrict__ bq, float* __restrict__ rk)
{
    const int bx = blockIdx.x;
    if (bx < 6144) {
        split_body(x, xh, xl, bx * 256 + threadIdx.x);
    } else if (bx < 13056) {
        split_body(Wq, Wqh, Wql, (bx - 6144) * 256 + threadIdx.x);
    } else if (bx < 19968) {
        split_body(Wk, Wkh, Wkl, (bx - 13056) * 256 + threadIdx.x);
    } else {
        const int idx = bx - 19968;            // [0,2304)
        const int h = idx / 192;
        const int d = (idx % 192) * 4 + ((int)threadIdx.x >> 6);
        const int lane = threadIdx.x & 63;
        const float4* row = (const float4*)(Wk + ((long)h * ND + d) * ND);
        const float4* bv4 = (const float4*)(bq + h * ND);
        float acc = 0.f;
        #pragma unroll
        for (int i = 0; i < 3; i++) {
            float4 a = row[lane + (i << 6)];
            float4 b = bv4[lane + (i << 6)];
            acc += a.x * b.x + a.y * b.y + a.z * b.z + a.w * b.w;
        }
        #pragma unroll
        for (int o = 32; o > 0; o >>= 1) acc += __shfl_xor(acc, o);
        if (lane == 0) rk[h * ND + d] = acc;
    }
}

__global__ __launch_bounds__(256, 2) void k_setup2(
    const unsigned short* __restrict__ Wkh, const unsigned short* __restrict__ Wkl,
    const unsigned short* __restrict__ Wqh, const unsigned short* __restrict__ Wql,
    unsigned short* __restrict__ MTh, unsigned short* __restrict__ MTl,
    const float* __restrict__ x, const float* __restrict__ rk, float* __restrict__ w_all)
{
    __shared__ __align__(16) char smem[65536];
    const int bx = blockIdx.x;
    if (bx < 432) {
        const int tid = (bx & 7) * 54 + (bx >> 3);   // XCD-contiguous tiles
        const int n0 = (tid % 6) << 7;
        const int m0 = ((tid / 6) % 6) << 7;
        const long hw = (long)(tid / 36) * (ND * ND);
        unsigned short* oh = MTh + hw + (long)m0 * ND + n0;
        unsigned short* ol = MTl + hw + (long)m0 * ND + n0;
        gemm_core64<3>(smem, Wkh + hw + (long)m0 * ND, Wkl + hw + (long)m0 * ND, ND,
                       Wqh + hw + (long)n0 * ND, Wql + hw + (long)n0 * ND, ND, ND,
                       [=](int r, int c, float v) {
                           unsigned short hh = f2bf(v);
                           oh[r * ND + c] = hh;
                           ol[r * ND + c] = f2bf(v - bf2f(hh));
                       });
    } else {
        float* srk = (float*)smem;               // 9216 floats = 36KB
        for (int i = threadIdx.x; i < NH * ND; i += 256) srk[i] = rk[i];
        __syncthreads();
        const int row = (bx - 432) * 4 + ((int)threadIdx.x >> 6);
        const int lane = threadIdx.x & 63;
        const float4* xr = (const float4*)(x + (long)row * ND);
        float4 xa[3];
        #pragma unroll
        for (int i = 0; i < 3; i++) xa[i] = xr[lane + (i << 6)];
        for (int h = 0; h < NH; h++) {
            const float* r = srk + h * ND;
            float acc = 0.f;
            #pragma unroll
            for (int i = 0; i < 3; i++) {
                int e = (lane + (i << 6)) << 2;
                acc += xa[i].x * r[e] + xa[i].y * r[e + 1]
                     + xa[i].z * r[e + 2] + xa[i].w * r[e + 3];
            }
            #pragma unroll
            for (int o = 32; o > 0; o >>= 1) acc += __shfl_xor(acc, o);
            if (lane == 0) w_all[h * (NB * NS) + row] = acc;
        }
    }
}

__global__ void k_setup3(const float* __restrict__ Wv, unsigned short* __restrict__ Wvb,
                         const float* __restrict__ Wp, unsigned short* __restrict__ WpT)
{
    __shared__ float tile[64][65];
    const int bx = blockIdx.x;
    if (bx < 6912) {
        int i = bx * 256 + threadIdx.x;
        float4 v = ((const float4*)Wv)[i];
        ushort4 h;
        h.x = f2bf(v.x); h.y = f2bf(v.y); h.z = f2bf(v.z); h.w = f2bf(v.w);
        ((ushort4*)Wvb)[i] = h;
    } else {
        const int idx = bx - 6912;             // [0,1728)
        const int c0 = (idx % 12) * 64;
        const int r0 = ((idx / 12) % 12) * 64;
        const long zo = (long)(idx / 144) * (ND * ND);
        const float* in = Wp + zo;
        unsigned short* oh = WpT + zo;
        const int tc = threadIdx.x & 63, t4 = threadIdx.x >> 6;
        #pragma unroll
        for (int i = 0; i < 16; i++) {
            int r = (i << 2) + t4;
            tile[r][tc] = in[(long)(r0 + r) * ND + c0 + tc];
        }
        __syncthreads();
        #pragma unroll
        for (int i = 0; i < 16; i++) {
            int c = (i << 2) + t4;
            oh[(long)(c0 + c) * ND + r0 + tc] = f2bf(tile[tc][c]);
        }
    }
}

__global__ __launch_bounds__(256, 2) void k_setup4(
    const unsigned short* __restrict__ WpT, const unsigned short* __restrict__ Wvb,
    unsigned short* __restrict__ NTo, const float* __restrict__ bv,
    float* __restrict__ s_all)
{
    __shared__ __align__(16) char smem[32768];
    const int bx = blockIdx.x;
    if (bx < 432) {
        const int tid = (bx & 7) * 54 + (bx >> 3);   // XCD-contiguous tiles
        const int n0 = (tid % 6) << 7;
        const int m0 = ((tid / 6) % 6) << 7;
        const long hw = (long)(tid / 36) * (ND * ND);
        unsigned short* o = NTo + hw + (long)m0 * ND + n0;
        gemm_core64<1>(smem, WpT + hw + (long)m0 * ND, nullptr, ND,
                       Wvb + hw + (long)n0 * ND, nullptr, ND, ND,
                       [=](int r, int c, float v) { o[r * ND + c] = f2bf(v); });
    } else {
        const int idx = bx - 432;              // [0,2304)
        const int h = idx / 192;
        const int j = (idx % 192) * 4 + ((int)threadIdx.x >> 6);
        const int lane = threadIdx.x & 63;
        const ushort4* row = (const ushort4*)(WpT + ((long)h * ND + j) * ND);
        const float* bvh = bv + h * ND;
        float acc = 0.f;
        #pragma unroll
        for (int i = 0; i < 3; i++) {
            int c = lane + (i << 6);
            ushort4 u = row[c];
            int e = c << 2;
            acc += bf2f(u.x) * bvh[e] + bf2f(u.y) * bvh[e + 1]
                 + bf2f(u.z) * bvh[e + 2] + bf2f(u.w) * bvh[e + 3];
        }
        #pragma unroll
        for (int o = 32; o > 0; o >>= 1) acc += __shfl_xor(acc, o);
        if (lane == 0) s_all[h * ND + j] = acc;
    }
}

// ------------------------- per-head kernels (R9 verbatim) --------------------

__global__ __launch_bounds__(256, 2) void k_G0(
    const unsigned short* __restrict__ xh, const unsigned short* __restrict__ xl,
    const unsigned short* __restrict__ MTh, const unsigned short* __restrict__ MTl,
    unsigned short* __restrict__ Gh, unsigned short* __restrict__ Gl)
{
    __shared__ __align__(16) char smem[65536];
    const int bx = blockIdx.x;
    const int xcd = bx & 7, idx = bx >> 3;
    const int m0 = (xcd * 8 + idx / 6) << 7;
    const int n0 = (idx % 6) << 7;
    unsigned short* oh = Gh + (long)m0 * ND + n0;
    unsigned short* ol = Gl + (long)m0 * ND + n0;
    gemm_core64<3>(smem, xh + (long)m0 * ND, xl + (long)m0 * ND, ND,
                   MTh + (long)n0 * ND, MTl + (long)n0 * ND, ND, ND,
                   [=](int r, int c, float v) {
                       unsigned short hh = f2bf(v);
                       oh[(long)r * ND + c] = hh;
                       ol[(long)r * ND + c] = f2bf(v - bf2f(hh));
                   });
}

// fused: blocks [0,512) scores = G.x^T + w (xcd = batch);
//        blocks [512,896) Z = x*NT_h + s_h -> ZT slot (xcd-banded m).
__global__ __launch_bounds__(256, 2) void k_SZ(
    const unsigned short* __restrict__ Gh, const unsigned short* __restrict__ Gl,
    const unsigned short* __restrict__ xh, const unsigned short* __restrict__ xl,
    const float* __restrict__ wv, float* __restrict__ Sc,
    const unsigned short* __restrict__ NTh, const float* __restrict__ sh,
    unsigned short* __restrict__ ZT)
{
    __shared__ __align__(16) char smem[65536];
    const int bx = blockIdx.x;
    if (bx < 512) {
        const int bl = bx & 7, idx = bx >> 3;
        const int m0 = (idx >> 3) << 7;
        const int n0 = (idx & 7) << 7;
        const long ao = ((long)bl * NS + m0) * ND;
        const long bo = ((long)bl * NS + n0) * ND;
        const float* ww = wv + bl * NS + n0;
        float* out = Sc + ((long)bl * NS + m0) * NS + n0;
        gemm_core64<3>(smem, Gh + ao, Gl + ao, ND, xh + bo, xl + bo, ND, ND,
                       [=](int r, int c, float v) { out[(long)r * NS + c] = v + ww[c]; });
    } else {
        const int g = bx - 512;
        const int xcd = g & 7, idx = g >> 3;
        const int m0 = (xcd * 8 + idx / 6) << 7;
        const int n0 = (idx % 6) << 7;
        const int bl = m0 >> 10;
        const int s0 = m0 & (NS - 1);
        unsigned short* zt = ZT + (long)bl * (ND * NS);
        gemm_core64<1>(smem, xh + (long)m0 * ND, nullptr, ND,
                       NTh + (long)n0 * ND, nullptr, ND, ND,
                       [=](int r, int c, float v) {
                           zt[(long)(n0 + c) * NS + s0 + r] = f2bf(v + sh[n0 + c]);
                       });
    }
}

// -------- fallback path (R9 verbatim): in-place softmax + PVG ---------------
__global__ __launch_bounds__(256) void k_SM(float* __restrict__ Sc) {
    int row = blockIdx.x * 4 + ((int)threadIdx.x >> 6);
    int lane = threadIdx.x & 63;
    float* rp = Sc + (long)row * NS;
    softmax_row_core(rp, (unsigned short*)rp, lane);
}

template<int MODE>   // 0: first head (write + bias), 1: accumulate
__global__ __launch_bounds__(256, 2) void k_PVG(
    const unsigned short* __restrict__ P, const unsigned short* __restrict__ ZT,
    const float* __restrict__ bp, float* __restrict__ outp,
    const unsigned short* __restrict__ xh, const unsigned short* __restrict__ xl,
    const unsigned short* __restrict__ MTh, const unsigned short* __restrict__ MTl,
    unsigned short* __restrict__ Gh, unsigned short* __restrict__ Gl)
{
    __shared__ __align__(16) char smem[65536];
    const int bx = blockIdx.x;
    if (bx < 384) {
        const int bl = bx & 7, idx = bx >> 3;
        const int m0 = (idx / 6) << 7;
        const int n0 = (idx % 6) << 7;
        const unsigned short* A = P + ((long)bl * NS + m0) * (2 * NS);
        const unsigned short* B = ZT + (long)bl * (ND * NS) + (long)n0 * NS;
        float* o = outp + ((long)bl * NS + m0) * ND + n0;
        const float* bi = bp + n0;
        gemm_core64<1>(smem, A, nullptr, 2 * NS, B, nullptr, NS, NS,
                       [=](int r, int c, float v) {
                           float* d = o + (long)r * ND + c;
                           if constexpr (MODE == 0) *d = v + bi[c];
                           else *d += v;
                       });
    } else {
        const int g = bx - 384;
        const int xcd = g & 7, idx = g >> 3;
        const int m0 = (xcd * 8 + idx / 6) << 7;
        const int n0 = (idx % 6) << 7;
        unsigned short* oh = Gh + (long)m0 * ND + n0;
        unsigned short* ol = Gl + (long)m0 * ND + n0;
        gemm_core64<3>(smem, xh + (long)m0 * ND, xl + (long)m0 * ND, ND,
                       MTh + (long)n0 * ND, MTl + (long)n0 * ND, ND, ND,
                       [=](int r, int c, float v) {
                           unsigned short hh = f2bf(v);
                           oh[(long)r * ND + c] = hh;
                           ol[(long)r * ND + c] = f2bf(v - bf2f(hh));
                       });
    }
}

// -------- grouped path: packed softmax + G, and grouped PV + next SZ --------

// blocks [0,2048): softmax Sc row -> packed Pp (stride NS); [2048,2432): G next.
__global__ __launch_bounds__(256, 2) void k_SMG(
    const float* __restrict__ Sc, unsigned short* __restrict__ Pp,
    const unsigned short* __restrict__ xh, const unsigned short* __restrict__ xl,
    const unsigned short* __restrict__ MTh, const unsigned short* __restrict__ MTl,
    unsigned short* __restrict__ Gh, unsigned short* __restrict__ Gl)
{
    __shared__ __align__(16) char smem[65536];
    const int bx = blockIdx.x;
    if (bx < 2048) {
        int row = bx * 4 + ((int)threadIdx.x >> 6);
        int lane = threadIdx.x & 63;
        softmax_row_core(Sc + (long)row * NS, Pp + (long)row * NS, lane);
    } else {
        const int g = bx - 2048;
        const int xcd = g & 7, idx = g >> 3;
        const int m0 = (xcd * 8 + idx / 6) << 7;
        const int n0 = (idx % 6) << 7;
        unsigned short* oh = Gh + (long)m0 * ND + n0;
        unsigned short* ol = Gl + (long)m0 * ND + n0;
        gemm_core64<3>(smem, xh + (long)m0 * ND, xl + (long)m0 * ND, ND,
                       MTh + (long)n0 * ND, MTl + (long)n0 * ND, ND, ND,
                       [=](int r, int c, float v) {
                           unsigned short hh = f2bf(v);
                           oh[(long)r * ND + c] = hh;
                           ol[(long)r * ND + c] = f2bf(v - bf2f(hh));
                       });
    }
}

// blocks [0,384): PV over NG heads (K = NG*1024, register accumulate, one
// d_out pass); [384,896): scores head hn; [896,1280): Z head hn -> ZTn.
template<int NG, int MODE>
__global__ __launch_bounds__(256, 2) void k_PVSZ(
    const unsigned short* __restrict__ Pp, const unsigned short* __restrict__ ZTb,
    int h0, const float* __restrict__ bp, float* __restrict__ outp,
    const unsigned short* __restrict__ Gh, const unsigned short* __restrict__ Gl,
    const unsigned short* __restrict__ xh, const unsigned short* __restrict__ xl,
    const float* __restrict__ wv, float* __restrict__ Sc,
    const unsigned short* __restrict__ NTh, const float* __restrict__ sh,
    unsigned short* __restrict__ ZTn)
{
    __shared__ __align__(16) char smem[65536];
    const int bx = blockIdx.x;
    if (bx < 384) {
        const size_t PPE = (size_t)(NB * NS) * NS;   // elems per Pp slot
        const size_t ZTE = (size_t)(NB * NS) * ND;   // elems per ZT slot
        const int bl = bx & 7, idx = bx >> 3;
        const int m0 = (idx / 6) << 7;
        const int n0 = (idx % 6) << 7;

        const int t = threadIdx.x;
        const int lane = t & 63;
        const int w = t >> 6;
        const int wm = (w >> 1) << 6;
        const int wn = (w & 1) << 6;
        const int lr = lane & 15;
        const int lg = lane >> 4;
        const int l3 = lane >> 3;
        const int cs = (lane & 7) ^ l3;
        const int ldsw = w << 12;
        // lda = ldb = NS ushorts = 2048 B for both operands
        const long gs = (long)(w * 32 + l3) * 2048 + cs * 16;
        const long gi = 16384;               // +8 rows, bytes
        char* smA = smem;
        char* smB = smem + 16384;

        int rowA[4], rowB[4];
        #pragma unroll
        for (int i = 0; i < 4; i++) {
            rowA[i] = (wm + (i << 4) + lr) << 6;
            rowB[i] = (wn + (i << 4) + lr) << 6;
        }
        const int lr7 = lr & 7;
        fx4 acc[4][4] = {};

        for (int j = 0; j < NG; j++) {
            const int sj = (h0 + j) % (NG + 1);
            const char* pA = (const char*)(Pp + (size_t)j * PPE
                                              + ((long)bl * NS + m0) * NS);
            const char* pB = (const char*)(ZTb + (size_t)sj * ZTE
                                              + (long)bl * (ND * NS) + (long)n0 * NS);
            for (int k0 = 0; k0 < NS; k0 += 64) {
                const long kb2 = (long)k0 * 2;
                __syncthreads();
                #pragma unroll
                for (int ii = 0; ii < 4; ii++) {
                    const int lo = ldsw + (ii << 10);
                    gll16(pA + gs + ii * gi + kb2, smA + lo);
                    gll16(pB + gs + ii * gi + kb2, smB + lo);
                }
                __syncthreads();
                #pragma unroll
                for (int kk = 0; kk < 2; kk++) {
                    const int pc = (((kk << 2) + lg) ^ lr7) << 3;
                    bf16x8 fa[4], fb[4];
                    #pragma unroll
                    for (int i = 0; i < 4; i++) {
                        fa[i] = *(const bf16x8*)((const unsigned short*)smA + rowA[i] + pc);
                        fb[i] = *(const bf16x8*)((const unsigned short*)smB + rowB[i] + pc);
                    }
                    #pragma unroll
                    for (int i = 0; i < 4; i++)
                        #pragma unroll
                        for (int jj = 0; jj < 4; jj++)
                            acc[i][jj] = __builtin_amdgcn_mfma_f32_16x16x32_bf16(
                                fa[i], fb[jj], acc[i][jj], 0, 0, 0);
                }
            }
        }
        float* o = outp + ((long)bl * NS + m0) * ND + n0;
        const float* bi = bp + n0;
        #pragma unroll
        for (int i = 0; i < 4; i++)
            #pragma unroll
            for (int jj = 0; jj < 4; jj++)
                #pragma unroll
                for (int r = 0; r < 4; r++) {
                    const int rr = wm + (i << 4) + (lg << 2) + r;
                    const int cc = wn + (jj << 4) + lr;
                    float* d = o + (long)rr * ND + cc;
                    if constexpr (MODE == 0) *d = acc[i][jj][r] + bi[cc];
                    else *d += acc[i][jj][r];
                }
    } else if (bx < 896) {
        const int b2 = bx - 384;
        const int bl = b2 & 7, idx = b2 >> 3;
        const int m0 = (idx >> 3) << 7;
        const int n0 = (idx & 7) << 7;
        const long ao = ((long)bl * NS + m0) * ND;
        const long bo = ((long)bl * NS + n0) * ND;
        const float* ww = wv + bl * NS + n0;
        float* out = Sc + ((long)bl * NS + m0) * NS + n0;
        gemm_core64<3>(smem, Gh + ao, Gl + ao, ND, xh + bo, xl + bo, ND, ND,
                       [=](int r, int c, float v) { out[(long)r * NS + c] = v + ww[c]; });
    } else {
        const int g = bx - 896;
        const int xcd = g & 7, idx = g >> 3;
        const int m0 = (xcd * 8 + idx / 6) << 7;
        const int n0 = (idx % 6) << 7;
        const int bl = m0 >> 10;
        const int s0 = m0 & (NS - 1);
        unsigned short* zt = ZTn + (long)bl * (ND * NS);
        gemm_core64<1>(smem, xh + (long)m0 * ND, nullptr, ND,
                       NTh + (long)n0 * ND, nullptr, ND, ND,
                       [=](int r, int c, float v) {
                           zt[(long)(n0 + c) * NS + s0 + r] = f2bf(v + sh[n0 + c]);
                       });
    }
}

// ---------------------------------------------------------------------------

extern "C" void kernel_launch(void* const* d_in, const int* in_sizes, int n_in,
                              void* d_out, int out_size, void* d_ws, size_t ws_size,
                              hipStream_t stream) {
    (void)in_sizes; (void)n_in; (void)out_size;
    const float* x  = (const float*)d_in[0];
    const float* Wq = (const float*)d_in[1];
    const float* bq = (const float*)d_in[2];
    const float* Wk = (const float*)d_in[3];
    const float* bk = (const float*)d_in[4];  (void)bk;  // cancels in softmax
    const float* Wv = (const float*)d_in[5];
    const float* bv = (const float*)d_in[6];
    const float* Wp = (const float*)d_in[7];
    const float* bp = (const float*)d_in[8];

    const size_t nx  = (size_t)NB * NS * ND;   // 6,291,456
    const size_t nw  = (size_t)NH * ND * ND;   // 7,077,888
    const size_t nwh = (size_t)ND * ND;        // per-head weight elems
    const size_t PPE = (size_t)NB * NS * NS;   // Pp slot elems (8,388,608)
    const size_t ZTE = (size_t)NB * NS * ND;   // ZT slot elems (6,291,456)

    char* p = (char*)d_ws;
    auto alloc = [&](size_t bytes) -> void* {
        void* r = (void*)p;
        p += (bytes + 255) & ~(size_t)255;
        return r;
    };
    // common persistent
    unsigned short* xh   = (unsigned short*)alloc(nx * 2);
    unsigned short* xl   = (unsigned short*)alloc(nx * 2);
    unsigned short* MTh  = (unsigned short*)alloc(nw * 2);
    unsigned short* MTl  = (unsigned short*)alloc(nw * 2);
    unsigned short* NTb  = (unsigned short*)alloc(nw * 2);
    float*          rk   = (float*)alloc((size_t)NH * ND * 4);
    float*          s_all= (float*)alloc((size_t)NH * ND * 4);
    float*          w_all= (float*)alloc((size_t)NH * NB * NS * 4);

    const size_t used_fixed = (size_t)(p - (char*)d_ws);
    const size_t scg = (PPE * 4 + 256) + 2 * (nx * 2 + 256);        // Sc + G
    const size_t slop = 2u << 20;
    auto need = [&](int ng) {
        return used_fixed + scg + (size_t)ng * (PPE * 2 + 256)
             + (size_t)(ng + 1) * (ZTE * 2 + 256) + slop;
    };
    int NG = 0;
    if (need(4) <= ws_size) NG = 4;
    else if (need(2) <= ws_size) NG = 2;

    if (NG) {
        // ---------------- grouped path ----------------
        float*          Sc = (float*)alloc(PPE * 4);
        unsigned short* Gh = (unsigned short*)alloc(nx * 2);
        unsigned short* Gl = (unsigned short*)alloc(nx * 2);
        unsigned short* Pp = (unsigned short*)alloc((size_t)NG * PPE * 2);
        unsigned short* ZT = (unsigned short*)alloc((size_t)(NG + 1) * ZTE * 2);
        // phase-A overlays at Sc (Sc+Gh+Gl = 58.7MB >= 56.6MB needed)
        unsigned short* Wqh = (unsigned short*)Sc;
        unsigned short* Wql = Wqh + nw;
        unsigned short* Wkh = Wql + nw;
        unsigned short* Wkl = Wkh + nw;
        unsigned short* Wvb = (unsigned short*)Sc;   // after MT done
        unsigned short* WpT = Wvb + nw;

        k_setup1<<<22272, 256, 0, stream>>>(x, xh, xl, Wq, Wqh, Wql, Wk, Wkh, Wkl, bq, rk);
        k_setup2<<<2480, 256, 0, stream>>>(Wkh, Wkl, Wqh, Wql, MTh, MTl, x, rk, w_all);
        k_setup3<<<8640, 256, 0, stream>>>(Wv, Wvb, Wp, WpT);
        k_setup4<<<2736, 256, 0, stream>>>(WpT, Wvb, NTb, bv, s_all);

        k_G0<<<384, 256, 0, stream>>>(xh, xl, MTh, MTl, Gh, Gl);
        k_SZ<<<896, 256, 0, stream>>>(Gh, Gl, xh, xl, w_all, Sc, NTb, s_all, ZT);
        const int NGR = NH / NG;
        for (int g = 0; g < NGR; g++) {
            for (int j = 0; j < NG; j++) {
                const int h = g * NG + j;
                if (j > 0)
                    k_SZ<<<896, 256, 0, stream>>>(
                        Gh, Gl, xh, xl, w_all + (long)h * NB * NS, Sc,
                        NTb + (long)h * nwh, s_all + h * ND,
                        ZT + (size_t)(h % (NG + 1)) * ZTE);
                const int hn = h + 1;
                const bool hasG = hn < NH;
                k_SMG<<<hasG ? 2432 : 2048, 256, 0, stream>>>(
                    Sc, Pp + (size_t)j * PPE, xh, xl,
                    MTh + (long)(hasG ? hn : 0) * nwh,
                    MTl + (long)(hasG ? hn : 0) * nwh, Gh, Gl);
            }
            const int hn = (g + 1) * NG;
            const bool tail = hn < NH;
            const int hs = tail ? hn : 0;
            const int grid = tail ? 1280 : 384;
            unsigned short* ZTn = ZT + (size_t)(hn % (NG + 1)) * ZTE;
            if (NG == 4) {
                if (g == 0)
                    k_PVSZ<4, 0><<<grid, 256, 0, stream>>>(
                        Pp, ZT, g * NG, bp, (float*)d_out, Gh, Gl, xh, xl,
                        w_all + (long)hs * NB * NS, Sc, NTb + (long)hs * nwh,
                        s_all + hs * ND, ZTn);
                else
                    k_PVSZ<4, 1><<<grid, 256, 0, stream>>>(
                        Pp, ZT, g * NG, bp, (float*)d_out, Gh, Gl, xh, xl,
                        w_all + (long)hs * NB * NS, Sc, NTb + (long)hs * nwh,
                        s_all + hs * ND, ZTn);
            } else {
                if (g == 0)
                    k_PVSZ<2, 0><<<grid, 256, 0, stream>>>(
                        Pp, ZT, g * NG, bp, (float*)d_out, Gh, Gl, xh, xl,
                        w_all + (long)hs * NB * NS, Sc, NTb + (long)hs * nwh,
                        s_all + hs * ND, ZTn);
                else
                    k_PVSZ<2, 1><<<grid, 256, 0, stream>>>(
                        Pp, ZT, g * NG, bp, (float*)d_out, Gh, Gl, xh, xl,
                        w_all + (long)hs * NB * NS, Sc, NTb + (long)hs * nwh,
                        s_all + hs * ND, ZTn);
            }
        }
    } else {
        // ---------------- R9-verbatim fallback ----------------
        char* U = (char*)alloc(2 * nx * 2 + PPE * 4 + ZTE * 2);
        unsigned short* Wqh = (unsigned short*)U;
        unsigned short* Wql = Wqh + nw;
        unsigned short* Wkh = Wql + nw;
        unsigned short* Wkl = Wkh + nw;
        unsigned short* Wvb = (unsigned short*)U;    // after MT done
        unsigned short* WpT = Wvb + nw;
        unsigned short* Gh = (unsigned short*)U;
        unsigned short* Gl = Gh + nx;
        float*          Sc = (float*)(Gl + nx);
        unsigned short* ZT = (unsigned short*)(Sc + PPE);

        k_setup1<<<22272, 256, 0, stream>>>(x, xh, xl, Wq, Wqh, Wql, Wk, Wkh, Wkl, bq, rk);
        k_setup2<<<2480, 256, 0, stream>>>(Wkh, Wkl, Wqh, Wql, MTh, MTl, x, rk, w_all);
        k_setup3<<<8640, 256, 0, stream>>>(Wv, Wvb, Wp, WpT);
        k_setup4<<<2736, 256, 0, stream>>>(WpT, Wvb, NTb, bv, s_all);

        k_G0<<<384, 256, 0, stream>>>(xh, xl, MTh, MTl, Gh, Gl);
        for (int h = 0; h < NH; h++) {
            const long hwn = (long)(h + 1) * nwh;
            k_SZ<<<896, 256, 0, stream>>>(Gh, Gl, xh, xl, w_all + (long)h * NB * NS,
                                          Sc, NTb + (long)h * nwh, s_all + h * ND, ZT);
            k_SM<<<2048, 256, 0, stream>>>(Sc);
            const int ng = (h + 1 < NH) ? 768 : 384;
            if (h == 0)
                k_PVG<0><<<ng, 256, 0, stream>>>((unsigned short*)Sc, ZT, bp,
                                                 (float*)d_out, xh, xl,
                                                 MTh + hwn, MTl + hwn, Gh, Gl);
            else
                k_PVG<1><<<ng, 256, 0, stream>>>((unsigned short*)Sc, ZT, bp,
                                                 (float*)d_out, xh, xl,
                                                 MTh + ((h + 1 < NH) ? hwn : 0),
                                                 MTl + ((h + 1 < NH) ? hwn : 0), Gh, Gl);
        }
    }
}

// Round 12
// 1363.347 us; speedup vs baseline: 1.0563x; 1.0397x over previous
//
#include <hip/hip_runtime.h>

// ---------------------------------------------------------------------------
// MultiHeadAttention (full-width per-head projections), MI355X gfx950.
// Round 12: launcher-level recombination of replay-verified kernels only.
//  - Setup 4->2 launches (Wvb/WpT overlay moved so Wv/Wp prep is independent
//    of MT; launchA = splits+rk+cast+transpose, launchB = MT+k_w+NT+sh).
//  - Per-head 3->2 launches, NG=1: k_SMG1 = softmax->Pp || G(h+1);
//    k_PVSZ1 = PV(h)->d_out(acc) || scores(h+1)->Sc || Z(h+1)->ZT slot.
//  - Working set 236 MB < 256 MB L3 (R11's NG=4 spilled L3 at 324 MB -> lost).
// All GEMM K-loops are the replay-verified gemm_core64 (single buffer,
// sync -> stage(global_load_lds) -> sync -> ds+MFMA, BK=64, swizzled).
// Math unchanged:
//   scores = softmax_t( 8*( x M_h x^T + w_t ) ),  M_h = Wq_h Wk_h^T
//   out    = sum_h P_h Z_h + bp,  Z_h = x N_h + bv_h Wp_h,  N_h = Wv_h Wp_h
// ---------------------------------------------------------------------------

typedef __attribute__((ext_vector_type(8))) short bf16x8;
typedef __attribute__((ext_vector_type(4))) float fx4;

#define NB 8
#define NS 1024
#define ND 768
#define NH 12

__device__ __forceinline__ unsigned short f2bf(float x) {
    unsigned int u = __float_as_uint(x);
    u += 0x7fffu + ((u >> 16) & 1u);   // round-to-nearest-even bf16
    return (unsigned short)(u >> 16);
}
__device__ __forceinline__ float bf2f(unsigned short h) {
    return __uint_as_float(((unsigned int)h) << 16);
}

// async global->LDS, 16B per lane; LDS base must be wave-uniform.
__device__ __forceinline__ void gll16(const void* g, void* l) {
    __builtin_amdgcn_global_load_lds(
        (const __attribute__((address_space(1))) void*)g,
        (__attribute__((address_space(3))) void*)l, 16, 0, 0);
}

// ---------------- elementwise body -------------------------------------------
__device__ __forceinline__ void split_body(const float* __restrict__ in,
                                           unsigned short* __restrict__ hi,
                                           unsigned short* __restrict__ lo, int i) {
    float4 v = ((const float4*)in)[i];
    ushort4 h, l;
    h.x = f2bf(v.x); l.x = f2bf(v.x - bf2f(h.x));
    h.y = f2bf(v.y); l.y = f2bf(v.y - bf2f(h.y));
    h.z = f2bf(v.z); l.z = f2bf(v.z - bf2f(h.z));
    h.w = f2bf(v.w); l.w = f2bf(v.w - bf2f(h.w));
    ((ushort4*)hi)[i] = h;
    ((ushort4*)lo)[i] = l;
}

// ---------------------------------------------------------------------------
// gemm_core64 — replay-verified (R9/R10/R11): 128x128 tile, BK=64, 4 waves,
// single-buffer, per K-tile: sync -> stage (global_load_lds) -> sync -> ds+MFMA.
// LDS [128][64] bf16 tiles (16KB each). Swizzle pc = c_log ^ (row&7);
// staging source chunk (lane&7)^(lane>>3), linear LDS dest -> 0 conflicts.
// C/D layout (HW-verified): col = lane&15, row = (lane>>4)*4 + reg.
// ---------------------------------------------------------------------------
template<int NTERMS, class Epi>
__device__ __forceinline__ void gemm_core64(
    char* __restrict__ smem,
    const unsigned short* __restrict__ Ah, const unsigned short* __restrict__ Al, int lda,
    const unsigned short* __restrict__ Bh, const unsigned short* __restrict__ Bl, int ldb,
    int K, Epi epi)
{
    constexpr int TILE = 16384;              // bytes per [128][64] bf16 tile

    const int t = threadIdx.x;
    const int lane = t & 63;
    const int w = t >> 6;
    const int wm = (w >> 1) << 6;
    const int wn = (w & 1) << 6;
    const int lr = lane & 15;
    const int lg = lane >> 4;

    const int l3 = lane >> 3;
    const int cs = (lane & 7) ^ l3;
    const int ldsw = w << 12;                // wave-uniform LDS byte offset

    const long gsA = (long)(w * 32 + l3) * lda * 2 + cs * 16;
    const long gsB = (long)(w * 32 + l3) * ldb * 2 + cs * 16;
    const long giA = (long)lda * 16;         // +8 rows, in bytes
    const long giB = (long)ldb * 16;

    const char* pAh = (const char*)Ah;
    const char* pBh = (const char*)Bh;
    const char* pAl = (const char*)Al;
    const char* pBl = (const char*)Bl;
    char* smA  = smem;
    char* smB  = smem + TILE;
    char* smA2 = smem + ((NTERMS == 3) ? 2 * TILE : 0);
    char* smB2 = smem + ((NTERMS == 3) ? 3 * TILE : TILE);

    int rowA[4], rowB[4];
    #pragma unroll
    for (int i = 0; i < 4; i++) {
        rowA[i] = (wm + (i << 4) + lr) << 6;   // ushort index of row base
        rowB[i] = (wn + (i << 4) + lr) << 6;
    }
    const int lr7 = lr & 7;

    fx4 acc[4][4] = {};

    for (int k0 = 0; k0 < K; k0 += 64) {
        const long kb2 = (long)k0 * 2;
        __syncthreads();
        #pragma unroll
        for (int ii = 0; ii < 4; ii++) {
            const int lo = ldsw + (ii << 10);
            gll16(pAh + gsA + ii * giA + kb2, smA + lo);
            gll16(pBh + gsB + ii * giB + kb2, smB + lo);
            if constexpr (NTERMS == 3) {
                gll16(pAl + gsA + ii * giA + kb2, smA2 + lo);
                gll16(pBl + gsB + ii * giB + kb2, smB2 + lo);
            }
        }
        __syncthreads();

        #pragma unroll
        for (int kk = 0; kk < 2; kk++) {
            const int pc = (((kk << 2) + lg) ^ lr7) << 3;   // ushort offset
            bf16x8 fa[4], fb[4], fa2[4], fb2[4];
            #pragma unroll
            for (int i = 0; i < 4; i++) {
                fa[i] = *(const bf16x8*)((const unsigned short*)smA + rowA[i] + pc);
                fb[i] = *(const bf16x8*)((const unsigned short*)smB + rowB[i] + pc);
            }
            if constexpr (NTERMS == 3) {
                #pragma unroll
                for (int i = 0; i < 4; i++) {
                    fa2[i] = *(const bf16x8*)((const unsigned short*)smA2 + rowA[i] + pc);
                    fb2[i] = *(const bf16x8*)((const unsigned short*)smB2 + rowB[i] + pc);
                }
            }
            #pragma unroll
            for (int i = 0; i < 4; i++)
                #pragma unroll
                for (int j = 0; j < 4; j++) {
                    acc[i][j] = __builtin_amdgcn_mfma_f32_16x16x32_bf16(fa[i], fb[j], acc[i][j], 0, 0, 0);
                    if constexpr (NTERMS == 3) {
                        acc[i][j] = __builtin_amdgcn_mfma_f32_16x16x32_bf16(fa[i], fb2[j], acc[i][j], 0, 0, 0);
                        acc[i][j] = __builtin_amdgcn_mfma_f32_16x16x32_bf16(fa2[i], fb[j], acc[i][j], 0, 0, 0);
                    }
                }
        }
    }

    #pragma unroll
    for (int i = 0; i < 4; i++)
        #pragma unroll
        for (int j = 0; j < 4; j++)
            #pragma unroll
            for (int r = 0; r < 4; r++)
                epi(wm + (i << 4) + (lg << 2) + r, wn + (j << 4) + lr, acc[i][j][r]);
}

// ---------------- softmax body (wave per row) --------------------------------
__device__ __forceinline__ void softmax_row_core(const float* __restrict__ rp,
                                                 unsigned short* __restrict__ drow,
                                                 int lane) {
    const float4* src = (const float4*)rp + (lane << 2);
    float v[16];
    #pragma unroll
    for (int i = 0; i < 4; i++) {
        float4 a = src[i];
        v[i * 4 + 0] = a.x; v[i * 4 + 1] = a.y; v[i * 4 + 2] = a.z; v[i * 4 + 3] = a.w;
    }
    float m = v[0];
    #pragma unroll
    for (int i = 1; i < 16; i++) m = fmaxf(m, v[i]);
    #pragma unroll
    for (int o = 32; o > 0; o >>= 1) m = fmaxf(m, __shfl_xor(m, o));
    float s = 0.f, p[16];
    #pragma unroll
    for (int i = 0; i < 16; i++) { p[i] = __expf((v[i] - m) * 8.0f); s += p[i]; }
    #pragma unroll
    for (int o = 32; o > 0; o >>= 1) s += __shfl_xor(s, o);
    float inv = 1.0f / s;
    unsigned int wrd[8];
    #pragma unroll
    for (int i = 0; i < 8; i++) {
        unsigned int u0 = f2bf(p[2 * i] * inv);
        unsigned int u1 = f2bf(p[2 * i + 1] * inv);
        wrd[i] = u0 | (u1 << 16);
    }
    uint4* dst = (uint4*)(drow + (lane << 4));
    dst[0] = make_uint4(wrd[0], wrd[1], wrd[2], wrd[3]);
    dst[1] = make_uint4(wrd[4], wrd[5], wrd[6], wrd[7]);
}

// ------------------------- merged setup launch A -----------------------------
// [0,6144) x split | [6144,13056) Wq split | [13056,19968) Wk split |
// [19968,22272) rk | [22272,29184) Wv cast | [29184,30912) Wp transpose.
__global__ void k_su_a(
    const float* __restrict__ x, unsigned short* __restrict__ xh, unsigned short* __restrict__ xl,
    const float* __restrict__ Wq, unsigned short* __restrict__ Wqh, unsigned short* __restrict__ Wql,
    const float* __restrict__ Wk, unsigned short* __restrict__ Wkh, unsigned short* __restrict__ Wkl,
    const float* __restrict__ bq, float* __restrict__ rk,
    const float* __restrict__ Wv, unsigned short* __restrict__ Wvb,
    const float* __restrict__ Wp, unsigned short* __restrict__ WpT)
{
    __shared__ float tile[64][65];
    const int bx = blockIdx.x;
    if (bx < 6144) {
        split_body(x, xh, xl, bx * 256 + threadIdx.x);
    } else if (bx < 13056) {
        split_body(Wq, Wqh, Wql, (bx - 6144) * 256 + threadIdx.x);
    } else if (bx < 19968) {
        split_body(Wk, Wkh, Wkl, (bx - 13056) * 256 + threadIdx.x);
    } else if (bx < 22272) {
        const int idx = bx - 19968;            // [0,2304)
        const int h = idx / 192;
        const int d = (idx % 192) * 4 + ((int)threadIdx.x >> 6);
        const int lane = threadIdx.x & 63;
        const float4* row = (const float4*)(Wk + ((long)h * ND + d) * ND);
        const float4* bv4 = (const float4*)(bq + h * ND);
        float acc = 0.f;
        #pragma unroll
        for (int i = 0; i < 3; i++) {
            float4 a = row[lane + (i << 6)];
            float4 b = bv4[lane + (i << 6)];
            acc += a.x * b.x + a.y * b.y + a.z * b.z + a.w * b.w;
        }
        #pragma unroll
        for (int o = 32; o > 0; o >>= 1) acc += __shfl_xor(acc, o);
        if (lane == 0) rk[h * ND + d] = acc;
    } else if (bx < 29184) {
        int i = (bx - 22272) * 256 + threadIdx.x;
        float4 v = ((const float4*)Wv)[i];
        ushort4 h;
        h.x = f2bf(v.x); h.y = f2bf(v.y); h.z = f2bf(v.z); h.w = f2bf(v.w);
        ((ushort4*)Wvb)[i] = h;
    } else {
        const int idx = bx - 29184;            // [0,1728)
        const int c0 = (idx % 12) * 64;
        const int r0 = ((idx / 12) % 12) * 64;
        const long zo = (long)(idx / 144) * (ND * ND);
        const float* in = Wp + zo;
        unsigned short* oh = WpT + zo;
        const int tc = threadIdx.x & 63, t4 = threadIdx.x >> 6;
        #pragma unroll
        for (int i = 0; i < 16; i++) {
            int r = (i << 2) + t4;
            tile[r][tc] = in[(long)(r0 + r) * ND + c0 + tc];
        }
        __syncthreads();
        #pragma unroll
        for (int i = 0; i < 16; i++) {
            int c = (i << 2) + t4;
            oh[(long)(c0 + c) * ND + r0 + tc] = f2bf(tile[tc][c]);
        }
    }
}

// ------------------------- merged setup launch B -----------------------------
// [0,432) MT (3-term, XCD-chunked) | [432,2480) k_w | [2480,2912) NT (1-term,
// XCD-chunked) | [2912,5216) sh.
__global__ __launch_bounds__(256, 2) void k_su_b(
    const unsigned short* __restrict__ Wkh, const unsigned short* __restrict__ Wkl,
    const unsigned short* __restrict__ Wqh, const unsigned short* __restrict__ Wql,
    unsigned short* __restrict__ MTh, unsigned short* __restrict__ MTl,
    const float* __restrict__ x, const float* __restrict__ rk, float* __restrict__ w_all,
    const unsigned short* __restrict__ WpT, const unsigned short* __restrict__ Wvb,
    unsigned short* __restrict__ NTo, const float* __restrict__ bv,
    float* __restrict__ s_all)
{
    __shared__ __align__(16) char smem[65536];
    const int bx = blockIdx.x;
    if (bx < 432) {
        const int tid = (bx & 7) * 54 + (bx >> 3);   // XCD-contiguous tiles
        const int n0 = (tid % 6) << 7;
        const int m0 = ((tid / 6) % 6) << 7;
        const long hw = (long)(tid / 36) * (ND * ND);
        unsigned short* oh = MTh + hw + (long)m0 * ND + n0;
        unsigned short* ol = MTl + hw + (long)m0 * ND + n0;
        gemm_core64<3>(smem, Wkh + hw + (long)m0 * ND, Wkl + hw + (long)m0 * ND, ND,
                       Wqh + hw + (long)n0 * ND, Wql + hw + (long)n0 * ND, ND, ND,
                       [=](int r, int c, float v) {
                           unsigned short hh = f2bf(v);
                           oh[r * ND + c] = hh;
                           ol[r * ND + c] = f2bf(v - bf2f(hh));
                       });
    } else if (bx < 2480) {
        float* srk = (float*)smem;               // 9216 floats = 36KB
        for (int i = threadIdx.x; i < NH * ND; i += 256) srk[i] = rk[i];
        __syncthreads();
        const int row = (bx - 432) * 4 + ((int)threadIdx.x >> 6);
        const int lane = threadIdx.x & 63;
        const float4* xr = (const float4*)(x + (long)row * ND);
        float4 xa[3];
        #pragma unroll
        for (int i = 0; i < 3; i++) xa[i] = xr[lane + (i << 6)];
        for (int h = 0; h < NH; h++) {
            const float* r = srk + h * ND;
            float acc = 0.f;
            #pragma unroll
            for (int i = 0; i < 3; i++) {
                int e = (lane + (i << 6)) << 2;
                acc += xa[i].x * r[e] + xa[i].y * r[e + 1]
                     + xa[i].z * r[e + 2] + xa[i].w * r[e + 3];
            }
            #pragma unroll
            for (int o = 32; o > 0; o >>= 1) acc += __shfl_xor(acc, o);
            if (lane == 0) w_all[h * (NB * NS) + row] = acc;
        }
    } else if (bx < 2912) {
        const int b2 = bx - 2480;
        const int tid = (b2 & 7) * 54 + (b2 >> 3);   // XCD-contiguous tiles
        const int n0 = (tid % 6) << 7;
        const int m0 = ((tid / 6) % 6) << 7;
        const long hw = (long)(tid / 36) * (ND * ND);
        unsigned short* o = NTo + hw + (long)m0 * ND + n0;
        gemm_core64<1>(smem, WpT + hw + (long)m0 * ND, nullptr, ND,
                       Wvb + hw + (long)n0 * ND, nullptr, ND, ND,
                       [=](int r, int c, float v) { o[r * ND + c] = f2bf(v); });
    } else {
        const int idx = bx - 2912;             // [0,2304)
        const int h = idx / 192;
        const int j = (idx % 192) * 4 + ((int)threadIdx.x >> 6);
        const int lane = threadIdx.x & 63;
        const ushort4* row = (const ushort4*)(WpT + ((long)h * ND + j) * ND);
        const float* bvh = bv + h * ND;
        float acc = 0.f;
        #pragma unroll
        for (int i = 0; i < 3; i++) {
            int c = lane + (i << 6);
            ushort4 u = row[c];
            int e = c << 2;
            acc += bf2f(u.x) * bvh[e] + bf2f(u.y) * bvh[e + 1]
                 + bf2f(u.z) * bvh[e + 2] + bf2f(u.w) * bvh[e + 3];
        }
        #pragma unroll
        for (int o = 32; o > 0; o >>= 1) acc += __shfl_xor(acc, o);
        if (lane == 0) s_all[h * ND + j] = acc;
    }
}

// ------------------------- per-head kernels ----------------------------------

// G = x * M_h (split out), head-0 bootstrap. flat grid 384 (R9 verbatim).
__global__ __launch_bounds__(256, 2) void k_G0(
    const unsigned short* __restrict__ xh, const unsigned short* __restrict__ xl,
    const unsigned short* __restrict__ MTh, const unsigned short* __restrict__ MTl,
    unsigned short* __restrict__ Gh, unsigned short* __restrict__ Gl)
{
    __shared__ __align__(16) char smem[65536];
    const int bx = blockIdx.x;
    const int xcd = bx & 7, idx = bx >> 3;
    const int m0 = (xcd * 8 + idx / 6) << 7;
    const int n0 = (idx % 6) << 7;
    unsigned short* oh = Gh + (long)m0 * ND + n0;
    unsigned short* ol = Gl + (long)m0 * ND + n0;
    gemm_core64<3>(smem, xh + (long)m0 * ND, xl + (long)m0 * ND, ND,
                   MTh + (long)n0 * ND, MTl + (long)n0 * ND, ND, ND,
                   [=](int r, int c, float v) {
                       unsigned short hh = f2bf(v);
                       oh[(long)r * ND + c] = hh;
                       ol[(long)r * ND + c] = f2bf(v - bf2f(hh));
                   });
}

// bootstrap: scores(0)+Z(0) (R9 k_SZ verbatim). grid 896.
__global__ __launch_bounds__(256, 2) void k_SZ(
    const unsigned short* __restrict__ Gh, const unsigned short* __restrict__ Gl,
    const unsigned short* __restrict__ xh, const unsigned short* __restrict__ xl,
    const float* __restrict__ wv, float* __restrict__ Sc,
    const unsigned short* __restrict__ NTh, const float* __restrict__ sh,
    unsigned short* __restrict__ ZT)
{
    __shared__ __align__(16) char smem[65536];
    const int bx = blockIdx.x;
    if (bx < 512) {
        const int bl = bx & 7, idx = bx >> 3;
        const int m0 = (idx >> 3) << 7;
        const int n0 = (idx & 7) << 7;
        const long ao = ((long)bl * NS + m0) * ND;
        const long bo = ((long)bl * NS + n0) * ND;
        const float* ww = wv + bl * NS + n0;
        float* out = Sc + ((long)bl * NS + m0) * NS + n0;
        gemm_core64<3>(smem, Gh + ao, Gl + ao, ND, xh + bo, xl + bo, ND, ND,
                       [=](int r, int c, float v) { out[(long)r * NS + c] = v + ww[c]; });
    } else {
        const int g = bx - 512;
        const int xcd = g & 7, idx = g >> 3;
        const int m0 = (xcd * 8 + idx / 6) << 7;
        const int n0 = (idx % 6) << 7;
        const int bl = m0 >> 10;
        const int s0 = m0 & (NS - 1);
        unsigned short* zt = ZT + (long)bl * (ND * NS);
        gemm_core64<1>(smem, xh + (long)m0 * ND, nullptr, ND,
                       NTh + (long)n0 * ND, nullptr, ND, ND,
                       [=](int r, int c, float v) {
                           zt[(long)(n0 + c) * NS + s0 + r] = f2bf(v + sh[n0 + c]);
                       });
    }
}

// blocks [0,2048): softmax Sc row -> packed Pp (stride NS); [2048,2432): G(h+1).
// (R11 k_SMG verbatim)
__global__ __launch_bounds__(256, 2) void k_SMG1(
    const float* __restrict__ Sc, unsigned short* __restrict__ Pp,
    const unsigned short* __restrict__ xh, const unsigned short* __restrict__ xl,
    const unsigned short* __restrict__ MTh, const unsigned short* __restrict__ MTl,
    unsigned short* __restrict__ Gh, unsigned short* __restrict__ Gl)
{
    __shared__ __align__(16) char smem[65536];
    const int bx = blockIdx.x;
    if (bx < 2048) {
        int row = bx * 4 + ((int)threadIdx.x >> 6);
        int lane = threadIdx.x & 63;
        softmax_row_core(Sc + (long)row * NS, Pp + (long)row * NS, lane);
    } else {
        const int g = bx - 2048;
        const int xcd = g & 7, idx = g >> 3;
        const int m0 = (xcd * 8 + idx / 6) << 7;
        const int n0 = (idx % 6) << 7;
        unsigned short* oh = Gh + (long)m0 * ND + n0;
        unsigned short* ol = Gl + (long)m0 * ND + n0;
        gemm_core64<3>(smem, xh + (long)m0 * ND, xl + (long)m0 * ND, ND,
                       MTh + (long)n0 * ND, MTl + (long)n0 * ND, ND, ND,
                       [=](int r, int c, float v) {
                           unsigned short hh = f2bf(v);
                           oh[(long)r * ND + c] = hh;
                           ol[(long)r * ND + c] = f2bf(v - bf2f(hh));
                       });
    }
}

// blocks [0,384): PV(h) = Pp . ZTr -> d_out (write/acc);
// [384,896): scores(h+1) -> Sc; [896,1280): Z(h+1) -> ZTw.
template<int MODE>   // 0: first head (write + bias), 1: accumulate
__global__ __launch_bounds__(256, 2) void k_PVSZ1(
    const unsigned short* __restrict__ Pp, const unsigned short* __restrict__ ZTr,
    const float* __restrict__ bp, float* __restrict__ outp,
    const unsigned short* __restrict__ Gh, const unsigned short* __restrict__ Gl,
    const unsigned short* __restrict__ xh, const unsigned short* __restrict__ xl,
    const float* __restrict__ wv, float* __restrict__ Sc,
    const unsigned short* __restrict__ NTh, const float* __restrict__ sh,
    unsigned short* __restrict__ ZTw)
{
    __shared__ __align__(16) char smem[65536];
    const int bx = blockIdx.x;
    if (bx < 384) {
        const int bl = bx & 7, idx = bx >> 3;
        const int m0 = (idx / 6) << 7;
        const int n0 = (idx % 6) << 7;
        const unsigned short* A = Pp + ((long)bl * NS + m0) * NS;
        const unsigned short* B = ZTr + (long)bl * (ND * NS) + (long)n0 * NS;
        float* o = outp + ((long)bl * NS + m0) * ND + n0;
        const float* bi = bp + n0;
        gemm_core64<1>(smem, A, nullptr, NS, B, nullptr, NS, NS,
                       [=](int r, int c, float v) {
                           float* d = o + (long)r * ND + c;
                           if constexpr (MODE == 0) *d = v + bi[c];
                           else *d += v;
                       });
    } else if (bx < 896) {
        const int b2 = bx - 384;
        const int bl = b2 & 7, idx = b2 >> 3;
        const int m0 = (idx >> 3) << 7;
        const int n0 = (idx & 7) << 7;
        const long ao = ((long)bl * NS + m0) * ND;
        const long bo = ((long)bl * NS + n0) * ND;
        const float* ww = wv + bl * NS + n0;
        float* out = Sc + ((long)bl * NS + m0) * NS + n0;
        gemm_core64<3>(smem, Gh + ao, Gl + ao, ND, xh + bo, xl + bo, ND, ND,
                       [=](int r, int c, float v) { out[(long)r * NS + c] = v + ww[c]; });
    } else {
        const int g = bx - 896;
        const int xcd = g & 7, idx = g >> 3;
        const int m0 = (xcd * 8 + idx / 6) << 7;
        const int n0 = (idx % 6) << 7;
        const int bl = m0 >> 10;
        const int s0 = m0 & (NS - 1);
        unsigned short* zt = ZTw + (long)bl * (ND * NS);
        gemm_core64<1>(smem, xh + (long)m0 * ND, nullptr, ND,
                       NTh + (long)n0 * ND, nullptr, ND, ND,
                       [=](int r, int c, float v) {
                           zt[(long)(n0 + c) * NS + s0 + r] = f2bf(v + sh[n0 + c]);
                       });
    }
}

// ---------------------------------------------------------------------------

extern "C" void kernel_launch(void* const* d_in, const int* in_sizes, int n_in,
                              void* d_out, int out_size, void* d_ws, size_t ws_size,
                              hipStream_t stream) {
    (void)in_sizes; (void)n_in; (void)out_size; (void)ws_size;
    const float* x  = (const float*)d_in[0];
    const float* Wq = (const float*)d_in[1];
    const float* bq = (const float*)d_in[2];
    const float* Wk = (const float*)d_in[3];
    const float* bk = (const float*)d_in[4];  (void)bk;  // cancels in softmax
    const float* Wv = (const float*)d_in[5];
    const float* bv = (const float*)d_in[6];
    const float* Wp = (const float*)d_in[7];
    const float* bp = (const float*)d_in[8];

    const size_t nx  = (size_t)NB * NS * ND;   // 6,291,456
    const size_t nw  = (size_t)NH * ND * ND;   // 7,077,888
    const size_t nwh = (size_t)ND * ND;
    const size_t PPE = (size_t)NB * NS * NS;   // Sc elems (8,388,608)
    const size_t ZTE = (size_t)NB * NS * ND;   // ZT slot elems

    char* p = (char*)d_ws;
    auto alloc = [&](size_t bytes) -> void* {
        void* r = (void*)p;
        p += (bytes + 255) & ~(size_t)255;
        return r;
    };
    // persistent (~110.6 MB)
    unsigned short* xh   = (unsigned short*)alloc(nx * 2);
    unsigned short* xl   = (unsigned short*)alloc(nx * 2);
    unsigned short* MTh  = (unsigned short*)alloc(nw * 2);
    unsigned short* MTl  = (unsigned short*)alloc(nw * 2);
    unsigned short* NTb  = (unsigned short*)alloc(nw * 2);
    float*          rk   = (float*)alloc((size_t)NH * ND * 4);
    float*          s_all= (float*)alloc((size_t)NH * ND * 4);
    float*          w_all= (float*)alloc((size_t)NH * NB * NS * 4);
    // phase-B arena (~125.8 MB): Sc, G, Pp, 2x ZT  (total ws ~236 MB)
    float*          Sc = (float*)alloc(PPE * 4);
    unsigned short* Gh = (unsigned short*)alloc(nx * 2);
    unsigned short* Gl = (unsigned short*)alloc(nx * 2);
    unsigned short* Pp = (unsigned short*)alloc(PPE * 2);
    unsigned short* ZT = (unsigned short*)alloc(2 * ZTE * 2);
    // setup overlays inside the phase-B arena (dead until G0/SZ):
    // splits at Sc [0,56.6MB); Wvb/WpT at [56.6,84.9MB)
    unsigned short* Wqh = (unsigned short*)Sc;
    unsigned short* Wql = Wqh + nw;
    unsigned short* Wkh = Wql + nw;
    unsigned short* Wkl = Wkh + nw;
    unsigned short* Wvb = Wkl + nw;
    unsigned short* WpT = Wvb + nw;

    // ---------------- setup (2 fused launches) ----------------
    k_su_a<<<30912, 256, 0, stream>>>(x, xh, xl, Wq, Wqh, Wql, Wk, Wkh, Wkl,
                                      bq, rk, Wv, Wvb, Wp, WpT);
    k_su_b<<<5216, 256, 0, stream>>>(Wkh, Wkl, Wqh, Wql, MTh, MTl, x, rk, w_all,
                                     WpT, Wvb, NTb, bv, s_all);

    // ---------------- per-head pipeline (2 launches/head) ----------------
    k_G0<<<384, 256, 0, stream>>>(xh, xl, MTh, MTl, Gh, Gl);
    k_SZ<<<896, 256, 0, stream>>>(Gh, Gl, xh, xl, w_all, Sc, NTb, s_all, ZT);
    for (int h = 0; h < NH; h++) {
        const int hn = h + 1;
        const bool hasG = hn < NH;
        const int hs = hasG ? hn : 0;
        k_SMG1<<<hasG ? 2432 : 2048, 256, 0, stream>>>(
            Sc, Pp, xh, xl, MTh + (long)hs * nwh, MTl + (long)hs * nwh, Gh, Gl);
        unsigned short* ZTr = ZT + (size_t)(h & 1) * ZTE;
        unsigned short* ZTw = ZT + (size_t)(hn & 1) * ZTE;
        const int grid = hasG ? 1280 : 384;
        if (h == 0)
            k_PVSZ1<0><<<grid, 256, 0, stream>>>(
                Pp, ZTr, bp, (float*)d_out, Gh, Gl, xh, xl,
                w_all + (long)hs * NB * NS, Sc, NTb + (long)hs * nwh,
                s_all + hs * ND, ZTw);
        else
            k_PVSZ1<1><<<grid, 256, 0, stream>>>(
                Pp, ZTr, bp, (float*)d_out, Gh, Gl, xh, xl,
                w_all + (long)hs * NB * NS, Sc, NTb + (long)hs * nwh,
                s_all + hs * ND, ZTw);
    }
}